// Round 17
// baseline (342.815 us; speedup 1.0000x reference)
//
#include <hip/hip_runtime.h>

// ---------------------------------------------------------------------------
// ZSSR involution net, fp32. Round 17 = R15 + 2-px register-blocked einsum.
// e_kernel: tile 16x8 x group, thread = (2 adjacent px, ch-quad wave).
// X window shared across the px pair (49->28 b128/px); w packed [25 kpair]
// [64 pospair][4] -> b128 reads. Grid 616 (8 bands x 77), 12 waves/CU
// resident (LDS 46KB, launch_bounds(256,3)). All R15 invariants kept:
// s_load weights (wave-uniform k/rq), t-partial chain, band swizzle.
// Layout: x[4 g][136x136 px][16 ch] channel-last, 3-px zero border.
// ---------------------------------------------------------------------------

#define HH 130
#define SP 136               // padded row stride
#define PPL (SP*SP)          // 18496
#define GP (PPL*16)          // floats per group-plane
#define XBUF2 (4*GP)         // floats per feature buffer
#define TP1 (16900*16)       // one group-partial buffer [px][16]
#define OFF_TA (2*XBUF2)             // set A: 4 buffers
#define OFF_TB (OFF_TA + 4*TP1)      // set B: 4 buffers

// --- conv_in (3->64, 3x3, pad=2) + border zeroing + layer-0 t partials -----
__global__ __launch_bounds__(256) void conv_in_kernel(
        const float* __restrict__ inf, const float* __restrict__ W,
        const float* __restrict__ b, float* __restrict__ x0,
        float* __restrict__ x1, float* __restrict__ tpA,
        const float* __restrict__ redw0) {   // [16][64] layer 0
    const int tid = threadIdx.x;
    if (blockIdx.x >= 67) {
        int idx = ((blockIdx.x - 67)*4 + blockIdx.y)*256 + tid;
        if (idx < 3192) {                      // 1596 border px * 2 buffers
            int bsel = idx & 1, e = idx >> 1;
            int r, c;
            if (e < 816) { r = e/136; c = e%136; if (r >= 3) r += 130; }
            else { int j = e-816; r = 3 + j/6; int m = j%6; c = (m<3)? m : m+130; }
            float* base = (bsel ? x1 : x0) + ((size_t)r*SP + c)*16;
            float4 z = make_float4(0.f,0.f,0.f,0.f);
            #pragma unroll
            for (int g2 = 0; g2 < 4; ++g2)
                #pragma unroll
                for (int q = 0; q < 4; ++q)
                    *(float4*)(base + (size_t)g2*GP + q*4) = z;
        }
        return;
    }
    __shared__ float wl[448];          // [16 ch][27 taps] + bias[16]
    const int g = blockIdx.y;
    for (int i = tid; i < 448; i += 256)
        wl[i] = (i < 432) ? W[g*432 + i] : b[g*16 + (i-432)];
    __syncthreads();
    int px = blockIdx.x*256 + tid;
    int pxc = px < 16900 ? px : 16899;
    int h = pxc/130, w = pxc%130;
    float xv[27];
    #pragma unroll
    for (int i = 0; i < 3; ++i)
      #pragma unroll
      for (int ky = 0; ky < 3; ++ky) {
        int y = h - 2 + ky;
        #pragma unroll
        for (int kx = 0; kx < 3; ++kx) {
            int xx = w - 2 + kx;
            float v = 0.f;
            if ((unsigned)y < 128u && (unsigned)xx < 128u)
                v = inf[i*16384 + y*128 + xx];
            xv[i*9 + ky*3 + kx] = v;
        }
      }
    float acc[16];
    #pragma unroll
    for (int c = 0; c < 16; ++c) {
        float a = wl[432 + c];
        #pragma unroll
        for (int t = 0; t < 27; ++t) a += wl[c*27 + t] * xv[t];
        acc[c] = a;
    }
    if (px < 16900) {
        float* dst = x0 + (size_t)g*GP + ((size_t)(h+3)*SP + (w+3))*16;
        #pragma unroll
        for (int q = 0; q < 4; ++q)
            *(float4*)(dst + q*4) =
                make_float4(acc[q*4], acc[q*4+1], acc[q*4+2], acc[q*4+3]);
        // layer-0 t partial for group g (thread owns all 16 ch; s_load redw0)
        float* td = tpA + (size_t)g*TP1 + (size_t)px*16;
        #pragma unroll
        for (int rq = 0; rq < 4; ++rq) {
            float p0=0.f, p1=0.f, p2=0.f, p3=0.f;
            #pragma unroll
            for (int j = 0; j < 16; ++j) {
                float a = acc[j];
                p0 += redw0[(rq*4+0)*64 + g*16 + j]*a;
                p1 += redw0[(rq*4+1)*64 + g*16 + j]*a;
                p2 += redw0[(rq*4+2)*64 + g*16 + j]*a;
                p3 += redw0[(rq*4+3)*64 + g*16 + j]*a;
            }
            *(float4*)(td + rq*4) = make_float4(p0, p1, p2, p3);
        }
    }
}

// --- e_kernel v13: 16x8 tile, 2-px register-blocked einsum -----------------
// grid 616: band = wid&7, j = wid>>3 (0..76); sid = band*77+j (<612);
// T = sid>>2 (0..152), g = sid&3; ty = (T/9)*8, tx = (T%9)*16.
// 256 thr: cq = tid>>6 (wave), pos = tid&63 (posr = pos>>3, posc = pos&7;
// px pair at cols posc*2, posc*2+1).
// LDS: xl[4][14][24][4] 21504B (ol[128][20] aliases) +
//      uu2[6400] = wl2[25][64][4] (tl[128][20] aliases) 25600B = 47104B.
#define EHR 14
#define EHC 24               // 22 used halo cols, padded
__global__ __launch_bounds__(256, 3) void e_kernel(
        const float* __restrict__ x,
        const float* __restrict__ tread,  // 4 partial bufs, this layer
        float* __restrict__ twrite,       // 4 partial bufs, next layer
        const float* __restrict__ gamma, const float* __restrict__ beta,
        const float* __restrict__ spanw,  // [4 g][49 k][16 r]
        const float* __restrict__ spanb,  // [4 g][49]
        const float* __restrict__ redwn,  // [16][64] next layer
        float* __restrict__ xout,
        const int doNext)
{
    __shared__ float xl[4*EHR*EHC*4];     // halo; later aliased as ol[128][20]
    __shared__ float uu2[25*64*4];        // tl[128][20] then wl2[25][64][4]
    const int wid = blockIdx.x;
    const int sid = (wid & 7)*77 + (wid >> 3);
    if (sid >= 612) return;
    const int T = sid >> 2, g = sid & 3;
    const int ty = (T/9)*8, tx = (T%9)*16;
    const int tid = threadIdx.x;
    const int cq = __builtin_amdgcn_readfirstlane(tid >> 6);
    const int pos = tid & 63;
    const int posr = pos >> 3, posc = pos & 7;

    // ---- stage halo: 14 rows x 22 cols x 16 ch ----
    for (int i = tid; i < EHR*22*4; i += 256) {
        int q = i & 3, p = i >> 2;
        int r = p / 22, c = p % 22;
        int gr = ty + r, gc = tx + c;           // padded-buffer coords
        gr = gr < SP ? gr : SP-1;               // clamp lands in zero border
        gc = gc < SP ? gc : SP-1;
        float4 v = *(const float4*)(x + (size_t)g*GP
                                    + ((size_t)gr*SP + gc)*16 + q*4);
        *(float4*)&xl[((q*EHR + r)*EHC + c)*4] = v;
    }

    // ---- t dedup: 512 tasks (128 px x 4 quads), 2 per thread ----
    float* tl = uu2;                            // [128][20]
    for (int it = 0; it < 2; ++it) {
        int task = tid + it*256;
        int pxt = task >> 2, qd = task & 3;
        int hh = min(ty + (pxt >> 4), HH-1), ww = min(tx + (pxt & 15), HH-1);
        const size_t toff = ((size_t)hh*HH + ww)*16 + qd*4;
        float4 s = make_float4(0.f,0.f,0.f,0.f);
        #pragma unroll
        for (int gg = 0; gg < 4; ++gg) {
            float4 a = *(const float4*)(tread + (size_t)gg*TP1 + toff);
            s.x += a.x; s.y += a.y; s.z += a.z; s.w += a.w;
        }
        *(float4*)&tl[pxt*20 + qd*4] = s;
    }
    __syncthreads();                            // #1: tl complete

    // ---- w-gen: lane px = tid&127, kpair chunk by sub = tid>>7 (wave-unif) -
    {
        const int pxw = tid & 127;
        const int sub = __builtin_amdgcn_readfirstlane(tid >> 7);
        float t16[16];
        #pragma unroll
        for (int q = 0; q < 4; ++q) {
            float4 v = *(const float4*)&tl[pxw*20 + q*4];
            t16[q*4+0] = fmaxf(gamma[q*4+0]*v.x + beta[q*4+0], 0.f);
            t16[q*4+1] = fmaxf(gamma[q*4+1]*v.y + beta[q*4+1], 0.f);
            t16[q*4+2] = fmaxf(gamma[q*4+2]*v.z + beta[q*4+2], 0.f);
            t16[q*4+3] = fmaxf(gamma[q*4+3]*v.w + beta[q*4+3], 0.f);
        }
        __syncthreads();                        // #2: tl reads done
        const float* sw = spanw + g*784;        // k wave-uniform -> s_load
        const float* sb = spanb + g*49;
        float* wl2 = uu2;                       // [25][64][4]
        const int wslot = (pxw >> 1)*4 + (pxw & 1);
        for (int it = 0; it < 13; ++it) {
            int kp = sub + it*2;
            if (kp < 25) {
                int k0 = 2*kp, k1 = 2*kp + 1;
                float a0 = sb[k0];
                #pragma unroll
                for (int r = 0; r < 16; ++r) a0 += sw[k0*16 + r] * t16[r];
                float a1 = 0.f;
                if (k1 < 49) {
                    a1 = sb[k1];
                    #pragma unroll
                    for (int r = 0; r < 16; ++r) a1 += sw[k1*16 + r] * t16[r];
                }
                wl2[kp*256 + wslot]     = a0;
                wl2[kp*256 + wslot + 2] = a1;
            }
        }
    }
    __syncthreads();                            // #3: wl2 + halo complete

    // ---- einsum: 2 px x 4 ch per lane, shared X window ----
    const float* wl2 = uu2;
    float4 acc0 = make_float4(0.f,0.f,0.f,0.f);
    float4 acc1 = make_float4(0.f,0.f,0.f,0.f);
    const int c0 = posc*2;
    #pragma unroll
    for (int i = 0; i < 7; ++i) {
        const int row = posr + i;
        float4 xv[8];
        #pragma unroll
        for (int jj = 0; jj < 8; ++jj)
            xv[jj] = *(const float4*)&xl[((cq*EHR + row)*EHC + c0 + jj)*4];
        const int kb = (7*i) >> 1;
        float4 wv[4];
        #pragma unroll
        for (int m = 0; m < 4; ++m)
            wv[m] = *(const float4*)&wl2[(kb + m)*256 + pos*4];
        #pragma unroll
        for (int jj = 0; jj < 7; ++jj) {
            const int k = 7*i + jj;
            const int m = (k >> 1) - kb, sl = k & 1;
            float w0 = sl ? ((m==0)?wv[0].z:(m==1)?wv[1].z:(m==2)?wv[2].z:wv[3].z)
                          : ((m==0)?wv[0].x:(m==1)?wv[1].x:(m==2)?wv[2].x:wv[3].x);
            float w1 = sl ? ((m==0)?wv[0].w:(m==1)?wv[1].w:(m==2)?wv[2].w:wv[3].w)
                          : ((m==0)?wv[0].y:(m==1)?wv[1].y:(m==2)?wv[2].y:wv[3].y);
            acc0.x += w0*xv[jj].x;   acc0.y += w0*xv[jj].y;
            acc0.z += w0*xv[jj].z;   acc0.w += w0*xv[jj].w;
            acc1.x += w1*xv[jj+1].x; acc1.y += w1*xv[jj+1].y;
            acc1.z += w1*xv[jj+1].z; acc1.w += w1*xv[jj+1].w;
        }
    }

    const int h = ty + posr;
    const int w0c = tx + c0, w1c = w0c + 1;
    const bool v0 = (h < HH) && (w0c < HH);
    const bool v1 = (h < HH) && (w1c < HH);
    float4 o0 = make_float4(fmaxf(acc0.x,0.f), fmaxf(acc0.y,0.f),
                            fmaxf(acc0.z,0.f), fmaxf(acc0.w,0.f));
    float4 o1 = make_float4(fmaxf(acc1.x,0.f), fmaxf(acc1.y,0.f),
                            fmaxf(acc1.z,0.f), fmaxf(acc1.w,0.f));
    if (v0) *(float4*)(xout + (size_t)g*GP
                       + ((size_t)(h+3)*SP + (w0c+3))*16 + cq*4) = o0;
    if (v1) *(float4*)(xout + (size_t)g*GP
                       + ((size_t)(h+3)*SP + (w1c+3))*16 + cq*4) = o1;

    // ---- next-layer t partial: in-WG reduce via dead xl, plain stores -----
    if (doNext) {
        float* ol = xl;                         // [128][20]
        __syncthreads();                        // #4: einsum xl reads done
        const int px0 = posr*16 + c0;
        *(float4*)&ol[px0*20 + cq*4]       = o0;
        *(float4*)&ol[(px0+1)*20 + cq*4]   = o1;
        __syncthreads();                        // #5: ol complete
        // 512 tasks: px 128 x rq 4; rq = wave (uniform -> s_load redwn)
        const int rq = cq;
        for (int it = 0; it < 2; ++it) {
            int pxr = (tid & 63) | (it << 6);
            float p0=0.f, p1=0.f, p2=0.f, p3=0.f;
            #pragma unroll
            for (int jc = 0; jc < 16; ++jc) {
                float xv = ol[pxr*20 + jc];
                const int c = g*16 + jc;
                p0 += redwn[(rq*4+0)*64 + c]*xv;
                p1 += redwn[(rq*4+1)*64 + c]*xv;
                p2 += redwn[(rq*4+2)*64 + c]*xv;
                p3 += redwn[(rq*4+3)*64 + c]*xv;
            }
            int h2 = ty + (pxr >> 4), w2 = tx + (pxr & 15);
            if (h2 < HH && w2 < HH)
                *(float4*)(twrite + (size_t)g*TP1
                           + ((size_t)h2*HH + w2)*16 + rq*4) =
                    make_float4(p0, p1, p2, p3);
        }
    }
}

// --- conv_out (64->12, 3x3 valid) + PixelShuffle(2) ------------------------
__global__ __launch_bounds__(256) void conv_out_ps_kernel(
        const float* __restrict__ x, const float* __restrict__ W,
        const float* __restrict__ b, float* __restrict__ out)
{
    __shared__ float xh[64*120];   // [c][10 r][12 cl]
    __shared__ float wl[6912];     // 12*64*9
    const int tid = threadIdx.x;
    const int ty = blockIdx.y*8, tx = blockIdx.x*8;

    for (int idx = tid; idx < 6912; idx += 256) wl[idx] = W[idx];
    for (int idx = tid; idx < 1600; idx += 256) {
        int g = idx/400, rem = idx%400;
        int p100 = rem>>2, q = rem&3;
        int r = p100/10, cl = p100%10;
        float4 v = *(const float4*)(x + (size_t)g*GP
                     + ((size_t)(ty + r + 3)*SP + tx + cl + 3)*16 + q*4);
        int c0 = g*16 + q*4;
        xh[(c0+0)*120 + r*12 + cl] = v.x;
        xh[(c0+1)*120 + r*12 + cl] = v.y;
        xh[(c0+2)*120 + r*12 + cl] = v.z;
        xh[(c0+3)*120 + r*12 + cl] = v.w;
    }
    __syncthreads();

    const int wave = __builtin_amdgcn_readfirstlane(tid >> 6);
    const int lane = tid & 63;
    const int s = lane >> 2, cq = lane & 3;
    const int sr = s >> 1, pc0 = (s & 1)*4;
    float acc[3][4] = {};

    for (int c = cq*16; c < cq*16 + 16; ++c) {
        #pragma unroll
        for (int ky = 0; ky < 3; ++ky) {
            const float* xb = &xh[c*120 + (sr + ky)*12 + pc0];
            float4 xa = *(const float4*)xb;
            float2 xm = *(const float2*)(xb + 4);
            float xr[6] = {xa.x, xa.y, xa.z, xa.w, xm.x, xm.y};
            #pragma unroll
            for (int oj = 0; oj < 3; ++oj) {
                const float* wp = &wl[((wave*3 + oj)*64 + c)*9 + ky*3];
                #pragma unroll
                for (int kx = 0; kx < 3; ++kx) {
                    float wv = wp[kx];
                    #pragma unroll
                    for (int q = 0; q < 4; ++q)
                        acc[oj][q] += wv * xr[kx + q];
                }
            }
        }
    }

    #pragma unroll
    for (int oj = 0; oj < 3; ++oj)
        #pragma unroll
        for (int q = 0; q < 4; ++q) {
            float v = acc[oj][q];
            v += __shfl_xor(v, 1, 64);
            v += __shfl_xor(v, 2, 64);
            acc[oj][q] = v;
        }

    if (cq == 0) {
        #pragma unroll
        for (int oj = 0; oj < 3; ++oj) {
            int o = wave*3 + oj;
            float bo = b[o];
            int c3 = o >> 2, r = (o >> 1) & 1, s2 = o & 1;
            int h = ty + sr;
            #pragma unroll
            for (int q = 0; q < 4; ++q) {
                int w = tx + pc0 + q;
                out[c3*65536 + (2*h + r)*256 + 2*w + s2] = acc[oj][q] + bo;
            }
        }
    }
}

// ---------------------------------------------------------------------------
extern "C" void kernel_launch(void* const* d_in, const int* in_sizes, int n_in,
                              void* d_out, int out_size, void* d_ws, size_t ws_size,
                              hipStream_t stream) {
    const float* inf   = (const float*)d_in[0];
    const float* cinw  = (const float*)d_in[1];
    const float* cinb  = (const float*)d_in[2];
    const float* redw  = (const float*)d_in[3];
    const float* gam   = (const float*)d_in[4];
    const float* bet   = (const float*)d_in[5];
    const float* spw   = (const float*)d_in[6];
    const float* spb   = (const float*)d_in[7];
    const float* cow   = (const float*)d_in[8];
    const float* cob   = (const float*)d_in[9];

    float* ws = (float*)d_ws;
    float* x0 = ws;
    float* x1 = ws + XBUF2;
    float* tA = ws + OFF_TA;
    float* tB = ws + OFF_TB;

    conv_in_kernel<<<dim3(80, 4), 256, 0, stream>>>(
        inf, cinw, cinb, x0, x1, tA, redw);

    float* cur = x0; float* nxt = x1;
    for (int l = 0; l < 6; ++l) {
        const int doNext = (l < 5);
        float* tread  = (l & 1) ? tB : tA;
        float* twrite = (l & 1) ? tA : tB;
        e_kernel<<<616, 256, 0, stream>>>(
            cur, tread, twrite,
            gam + l*16, bet + l*16,
            spw + l*3136, spb + l*196,
            redw + (doNext ? (l+1)*1024 : 0),
            nxt, doNext);
        float* t = cur; cur = nxt; nxt = t;
    }

    conv_out_ps_kernel<<<dim3(16, 16), 256, 0, stream>>>(
        cur, cow, cob, (float*)d_out);
}